// Round 2
// 392.372 us; speedup vs baseline: 1.0266x; 1.0266x over previous
//
#include <hip/hip_runtime.h>
#include <stdint.h>

#define M_DIM 8192
#define N_DIM 4096
#define K_DIM 4096
#define NT    (K_DIM / 128)  // 32 K-tiles of 128 bytes

typedef __attribute__((ext_vector_type(4))) int int32x4;

// --- Fused prep kernel (unchanged) ---
#define QUANT_BLOCKS 2048
#define SIGN_BLOCKS  1024
#define SIGN_THREADS (SIGN_BLOCKS * 256)

__global__ __launch_bounds__(256) void prep_kernel(const float* __restrict__ x,
                                                   const float* __restrict__ w,
                                                   signed char* __restrict__ xq,
                                                   signed char* __restrict__ wq,
                                                   float* __restrict__ scales) {
  const int bid = blockIdx.x;
  const int t = threadIdx.x;
  if (bid < QUANT_BLOCKS) {
    const int wave = t >> 6, lane = t & 63;
    const int row = bid * 4 + wave;
    const float4* xr = (const float4*)(x + (size_t)row * K_DIM);
    float4 v[16];
    float amax = 0.f;
#pragma unroll
    for (int j = 0; j < 16; j++) {
      v[j] = xr[lane + 64 * j];
      amax = fmaxf(amax, fmaxf(fmaxf(fabsf(v[j].x), fabsf(v[j].y)),
                               fmaxf(fabsf(v[j].z), fabsf(v[j].w))));
    }
#pragma unroll
    for (int off = 32; off > 0; off >>= 1)
      amax = fmaxf(amax, __shfl_xor(amax, off, 64));
    amax = fmaxf(amax, 1e-30f);
    const float rsc = 127.0f / amax;
    if (lane == 0) scales[row] = amax / 127.0f;
    int* qr = (int*)(xq + (size_t)row * K_DIM);
#pragma unroll
    for (int j = 0; j < 16; j++) {
      int q0 = __float2int_rn(v[j].x * rsc);
      int q1 = __float2int_rn(v[j].y * rsc);
      int q2 = __float2int_rn(v[j].z * rsc);
      int q3 = __float2int_rn(v[j].w * rsc);
      qr[lane + 64 * j] = (q0 & 255) | ((q1 & 255) << 8) | ((q2 & 255) << 16) | (q3 << 24);
    }
  } else {
    const int idx0 = (bid - QUANT_BLOCKS) * 256 + t;
    const float4* wf = (const float4*)w;
    int4* o = (int4*)wq;
#pragma unroll
    for (int k = 0; k < 4; k++) {
      const int idx = idx0 + k * SIGN_THREADS;
      int4 pk;
      int* pi = (int*)&pk;
#pragma unroll
      for (int j = 0; j < 4; j++) {
        float4 a = wf[(size_t)idx * 4 + j];
        unsigned b0 = a.x >= 0.f ? 0x01u : 0xFFu;
        unsigned b1 = a.y >= 0.f ? 0x01u : 0xFFu;
        unsigned b2 = a.z >= 0.f ? 0x01u : 0xFFu;
        unsigned b3 = a.w >= 0.f ? 0x01u : 0xFFu;
        pi[j] = (int)(b0 | (b1 << 8) | (b2 << 16) | (b3 << 24));
      }
      o[idx] = pk;
    }
  }
}

// Async global->LDS, 16 B/lane. LDS dest = wave-uniform base + lane*16 (linear);
// the GLOBAL source is per-lane, which is how the XOR swizzle is applied
// (pre-swizzled source, linear dest, swizzled ds_read — both-sides-or-neither).
__device__ __forceinline__ void async16(const signed char* g, signed char* l) {
  __builtin_amdgcn_global_load_lds((const __attribute__((address_space(1))) void*)g,
                                   (__attribute__((address_space(3))) void*)l, 16, 0, 0);
}

// ============================================================================
// 256x256-tile, 8-wave, 8-phase i8 GEMM (T2+T3+T4+T5+T1 port of the bf16
// template; byte-geometry identical: BK=128B, 16B fragments, ds_read_b128).
//
// LDS map (128 KiB):  A: buf b at b*32768, [256 rows][128 B]
//                     B: buf b at 65536 + b*32768
// Swizzle: row r, logical 16B piece p stored at physical piece p ^ (r&7).
//
// Window W (4 phases) computes tile W from buf[W&1]:
//   phase 0: ds_read all 8 B-frags + A-quadrant0 (12 reads) | stage A0(W+1)
//   phase 1: A-quadrant1 (4 reads)                          | stage A1(W+1)
//   phase 2: A-quadrant2                                    | stage B0(W+2)
//   phase 3: A-quadrant3                                    | stage B1(W+2),
//            then vmcnt(4) (tile W+1 fully landed; B(W+2) stays in flight)
// Each phase: reads+stage | s_barrier | lgkmcnt(0)+sched_barrier(0) |
//             setprio(1) 16x MFMA setprio(0) | [tail] | s_barrier.
// Race-freedom: A(W+1) targets the buffer last READ in window W-1 (barriers
// between); B(W+2) targets current buffer's B region, whose fragment reads
// were drained by every wave's phase-0 lgkmcnt(0), two barriers before any
// wave can issue the phase-2 stage. vmcnt(4) BEFORE the window-end barrier
// makes every wave's staged contribution visible to all.
// Tail windows re-stage the last real K-tile into dead buffers (branch-free);
// a post-loop vmcnt(0)+barrier drains them so NO LDS-DMA is in flight when
// waves retire (in-flight global_load_lds past s_endpgm would land in a
// successor block's freed-and-reallocated LDS — round-1 hardening).
// ============================================================================

#define STAGE_A(b, h, k0)                                                      \
  do {                                                                         \
    async16(gA + (h) * (128L * K_DIM) + (k0),                                  \
            &lds[(b) * 32768 + (h) * 16384 + wave * 1024]);                    \
    async16(gA + (h) * (128L * K_DIM) + 64L * K_DIM + (k0),                    \
            &lds[(b) * 32768 + (h) * 16384 + 8192 + wave * 1024]);             \
  } while (0)

#define STAGE_B(b, h, k0)                                                      \
  do {                                                                         \
    async16(gB + (h) * (128L * K_DIM) + (k0),                                  \
            &lds[65536 + (b) * 32768 + (h) * 16384 + wave * 1024]);            \
    async16(gB + (h) * (128L * K_DIM) + 64L * K_DIM + (k0),                    \
            &lds[65536 + (b) * 32768 + (h) * 16384 + 8192 + wave * 1024]);     \
  } while (0)

#define PHASE(BUF, Q, STAGE_STMT, TAIL_STMT)                                   \
  {                                                                            \
    int32x4 af[2][2];                                                          \
    _Pragma("unroll") for (int i2 = 0; i2 < 2; ++i2)                           \
    _Pragma("unroll") for (int kk = 0; kk < 2; ++kk)                           \
      af[i2][kk] = *(const int32x4*)&lds[(BUF) * 32768 + aoff[kk] +            \
                                         (2 * (Q) + i2) * 2048];               \
    STAGE_STMT;                                                                \
    __builtin_amdgcn_s_barrier();                                              \
    asm volatile("s_waitcnt lgkmcnt(0)" ::: "memory");                         \
    __builtin_amdgcn_sched_barrier(0);                                         \
    __builtin_amdgcn_s_setprio(1);                                             \
    _Pragma("unroll") for (int kk = 0; kk < 2; ++kk)                           \
    _Pragma("unroll") for (int i2 = 0; i2 < 2; ++i2)                           \
    _Pragma("unroll") for (int fj = 0; fj < 4; ++fj)                           \
      acc[2 * (Q) + i2][fj] = __builtin_amdgcn_mfma_i32_16x16x64_i8(           \
          af[i2][kk], bfr[fj][kk], acc[2 * (Q) + i2][fj], 0, 0, 0);            \
    __builtin_amdgcn_s_setprio(0);                                             \
    TAIL_STMT;                                                                 \
    __builtin_amdgcn_s_barrier();                                              \
  }

#define WINDOW(BUF, KA, KB)                                                    \
  {                                                                            \
    int32x4 bfr[4][2];                                                         \
    _Pragma("unroll") for (int fj = 0; fj < 4; ++fj)                           \
    _Pragma("unroll") for (int kk = 0; kk < 2; ++kk)                           \
      bfr[fj][kk] =                                                            \
          *(const int32x4*)&lds[(BUF) * 32768 + boff[kk] + fj * 2048];         \
    PHASE(BUF, 0, STAGE_A(1 - (BUF), 0, KA), (void)0)                          \
    PHASE(BUF, 1, STAGE_A(1 - (BUF), 1, KA), (void)0)                          \
    PHASE(BUF, 2, STAGE_B(BUF, 0, KB), (void)0)                                \
    PHASE(BUF, 3, STAGE_B(BUF, 1, KB),                                         \
          asm volatile("s_waitcnt vmcnt(4)" ::: "memory"))                     \
  }

__global__ __launch_bounds__(512, 2) void gemm_i8_kernel(
    const signed char* __restrict__ A,
    const signed char* __restrict__ B,
    const float* __restrict__ scales,
    const float* __restrict__ bias,
    float* __restrict__ C) {
  __shared__ __align__(16) signed char lds[131072];

  const int tid  = threadIdx.x;
  const int wave = tid >> 6;
  const int lane = tid & 63;
  const int wm = wave >> 2;   // 0..1: M half (128 rows)
  const int wn = wave & 3;    // 0..3: N quarter (64 cols)
  const int qd = lane >> 4, l16 = lane & 15;

  // T1: XCD-aware swizzle (512 wgs, 512%8==0 -> simple form is bijective)
  int wg = blockIdx.x;
  wg = (wg & 7) * (512 / 8) + (wg >> 3);
  const int bx = wg & 15;   // 16 N-tiles
  const int by = wg >> 4;   // 32 M-tiles
  const long m0 = (long)by * 256;
  const long n0 = (long)bx * 256;

  // staging per-thread source: chunk c = i*512 + tid; row r = i*64 + (tid>>3),
  // physical piece s = tid&7 holds logical piece s ^ (r&7) -> source offset:
  const int roff = tid >> 3;
  const int poff = ((tid & 7) ^ ((tid >> 3) & 7)) << 4;
  const signed char* gA = A + (m0 + roff) * K_DIM + poff;
  const signed char* gB = B + (n0 + roff) * K_DIM + poff;

  // fragment read offsets: row = (wm*128|wn*64) + frag*16 + l16,
  // logical piece kk*4+qd at physical (kk*4+qd) ^ (l16&7)  [row&7 == l16&7]
  const int swz = l16 & 7;
  int aoff[2], boff[2];
#pragma unroll
  for (int kk = 0; kk < 2; ++kk) {
    const int pp = ((kk * 4 + qd) ^ swz) << 4;
    aoff[kk] = (wm * 128 + l16) * 128 + pp;
    boff[kk] = 65536 + (wn * 64 + l16) * 128 + pp;
  }

  int32x4 acc[8][4];
#pragma unroll
  for (int i = 0; i < 8; ++i)
#pragma unroll
    for (int j = 0; j < 4; ++j)
      acc[i][j] = (int32x4){0, 0, 0, 0};

  // prologue: tile0 (A+B) + tile1 B; vmcnt(4) -> tile0 landed, B(1) in flight
  STAGE_A(0, 0, 0);
  STAGE_A(0, 1, 0);
  STAGE_B(0, 0, 0);
  STAGE_B(0, 1, 0);
  STAGE_B(1, 0, 128);
  STAGE_B(1, 1, 128);
  asm volatile("s_waitcnt vmcnt(4)" ::: "memory");
  __builtin_amdgcn_s_barrier();

#pragma unroll 1
  for (int W = 0; W < NT; W += 2) {
    const long kA0 = (long)((W + 1 < NT) ? (W + 1) : (NT - 1)) * 128;
    const long kB0 = (long)((W + 2 < NT) ? (W + 2) : (NT - 1)) * 128;
    WINDOW(0, kA0, kB0)
    const long kA1 = (long)((W + 2 < NT) ? (W + 2) : (NT - 1)) * 128;
    const long kB1 = (long)((W + 3 < NT) ? (W + 3) : (NT - 1)) * 128;
    WINDOW(1, kA1, kB1)
  }

  // drain ALL in-flight LDS-DMA before any wave can retire (hardening: an
  // in-flight global_load_lds at s_endpgm writes into deallocated LDS).
  asm volatile("s_waitcnt vmcnt(0)" ::: "memory");
  __builtin_amdgcn_s_barrier();

  // epilogue: C/D layout col=lane&15, row=(lane>>4)*4+reg
  const long row0 = m0 + wm * 128 + qd * 4;
  const long col0 = n0 + wn * 64 + l16;
#pragma unroll
  for (int fj = 0; fj < 4; ++fj) {
    const float bv = bias[col0 + fj * 16];
#pragma unroll
    for (int fi = 0; fi < 8; ++fi) {
      const long r = row0 + fi * 16;
      float4 sv = *(const float4*)&scales[r];
      const float* s = &sv.x;
#pragma unroll
      for (int i = 0; i < 4; ++i) {
        C[(r + i) * N_DIM + col0 + fj * 16] = (float)acc[fi][fj][i] * s[i] + bv;
      }
    }
  }
}

extern "C" void kernel_launch(void* const* d_in, const int* in_sizes, int n_in,
                              void* d_out, int out_size, void* d_ws, size_t ws_size,
                              hipStream_t stream) {
  const float* x    = (const float*)d_in[0];   // [8192, 4096] fp32
  const float* w    = (const float*)d_in[1];   // [4096, 4096] fp32
  const float* bias = (const float*)d_in[2];   // [4096] fp32
  float* out = (float*)d_out;                  // [8192, 4096] fp32

  // workspace: X i8 (32 MB) | W sign i8 (16 MB) | row scales (32 KB)
  signed char* xq = (signed char*)d_ws;
  signed char* wq = xq + (size_t)M_DIM * K_DIM;
  float* scales   = (float*)(wq + (size_t)N_DIM * K_DIM);

  prep_kernel<<<QUANT_BLOCKS + SIGN_BLOCKS, 256, 0, stream>>>(x, w, xq, wq, scales);

  gemm_i8_kernel<<<dim3((M_DIM / 256) * (N_DIM / 256)), dim3(512), 0, stream>>>(
      xq, wq, scales, bias, out);
}

// Round 3
// 391.380 us; speedup vs baseline: 1.0292x; 1.0025x over previous
//
#include <hip/hip_runtime.h>
#include <stdint.h>

#define M_DIM 8192
#define N_DIM 4096
#define K_DIM 4096
#define NT    (K_DIM / 128)  // 32 K-tiles of 128 bytes

typedef __attribute__((ext_vector_type(4))) int int32x4;

// --- Fused prep kernel (unchanged) ---
#define QUANT_BLOCKS 2048
#define SIGN_BLOCKS  1024
#define SIGN_THREADS (SIGN_BLOCKS * 256)

__global__ __launch_bounds__(256) void prep_kernel(const float* __restrict__ x,
                                                   const float* __restrict__ w,
                                                   signed char* __restrict__ xq,
                                                   signed char* __restrict__ wq,
                                                   float* __restrict__ scales) {
  const int bid = blockIdx.x;
  const int t = threadIdx.x;
  if (bid < QUANT_BLOCKS) {
    const int wave = t >> 6, lane = t & 63;
    const int row = bid * 4 + wave;
    const float4* xr = (const float4*)(x + (size_t)row * K_DIM);
    float4 v[16];
    float amax = 0.f;
#pragma unroll
    for (int j = 0; j < 16; j++) {
      v[j] = xr[lane + 64 * j];
      amax = fmaxf(amax, fmaxf(fmaxf(fabsf(v[j].x), fabsf(v[j].y)),
                               fmaxf(fabsf(v[j].z), fabsf(v[j].w))));
    }
#pragma unroll
    for (int off = 32; off > 0; off >>= 1)
      amax = fmaxf(amax, __shfl_xor(amax, off, 64));
    amax = fmaxf(amax, 1e-30f);
    const float rsc = 127.0f / amax;
    if (lane == 0) scales[row] = amax / 127.0f;
    int* qr = (int*)(xq + (size_t)row * K_DIM);
#pragma unroll
    for (int j = 0; j < 16; j++) {
      int q0 = __float2int_rn(v[j].x * rsc);
      int q1 = __float2int_rn(v[j].y * rsc);
      int q2 = __float2int_rn(v[j].z * rsc);
      int q3 = __float2int_rn(v[j].w * rsc);
      qr[lane + 64 * j] = (q0 & 255) | ((q1 & 255) << 8) | ((q2 & 255) << 16) | (q3 << 24);
    }
  } else {
    const int idx0 = (bid - QUANT_BLOCKS) * 256 + t;
    const float4* wf = (const float4*)w;
    int4* o = (int4*)wq;
#pragma unroll
    for (int k = 0; k < 4; k++) {
      const int idx = idx0 + k * SIGN_THREADS;
      int4 pk;
      int* pi = (int*)&pk;
#pragma unroll
      for (int j = 0; j < 4; j++) {
        float4 a = wf[(size_t)idx * 4 + j];
        unsigned b0 = a.x >= 0.f ? 0x01u : 0xFFu;
        unsigned b1 = a.y >= 0.f ? 0x01u : 0xFFu;
        unsigned b2 = a.z >= 0.f ? 0x01u : 0xFFu;
        unsigned b3 = a.w >= 0.f ? 0x01u : 0xFFu;
        pi[j] = (int)(b0 | (b1 << 8) | (b2 << 16) | (b3 << 24));
      }
      o[idx] = pk;
    }
  }
}

// Async global->LDS, 16 B/lane. LDS dest = wave-uniform base + lane*16 (linear);
// the GLOBAL source is per-lane, which is how the XOR swizzle is applied
// (pre-swizzled source, linear dest, swizzled ds_read — both-sides-or-neither).
__device__ __forceinline__ void async16(const signed char* g, signed char* l) {
  __builtin_amdgcn_global_load_lds((const __attribute__((address_space(1))) void*)g,
                                   (__attribute__((address_space(3))) void*)l, 16, 0, 0);
}

// ============================================================================
// 256x256-tile, 8-wave, 8-phase i8 GEMM.
//
// Round-3 change: REMOVED the manual `s_waitcnt lgkmcnt(0)` + sched_barrier(0)
// before each MFMA cluster. Diagnosis (round-2 counters): phase time ~1430 cyc
// = MFMA 653 + LDS drain ~580 + barriers; the forced full drain serialized the
// LDS pipe with the MFMA pipe. Compiler-visible C++ ds_reads get exact counted
// lgkmcnt waits (m97: hipcc emits lgkmcnt(4/3/1/0) interleaved with MFMA), so
// the drain tail now overlaps the MFMA burst. Rule #18 does not apply (no
// inline-asm ds_reads). WAR safety unchanged: every read's value is consumed
// before that wave's phase-end barrier; overwriting stages are >=1 end-barrier
// later; vmcnt ledger protected (global_load_lds can't cross asm "memory").
//
// LDS map (128 KiB):  A: buf b at b*32768, [256 rows][128 B]
//                     B: buf b at 65536 + b*32768
// Swizzle: row r, logical 16B piece p stored at physical piece p ^ (r&7).
//
// Window W (4 phases) computes tile W from buf[W&1]:
//   phase 0: ds_read 8 B-frags + A-quadrant0 | stage A0(W+1)
//   phase 1: A-quadrant1                     | stage A1(W+1)
//   phase 2: A-quadrant2                     | stage B0(W+2)
//   phase 3: A-quadrant3                     | stage B1(W+2), vmcnt(4)
// Each phase: reads+stage | s_barrier | setprio(1) 16x MFMA (compiler-counted
// lgkm waits) setprio(0) | [tail] | s_barrier.
// vmcnt(4) at phase 3 => tile W+1 fully landed; B(W+2) stays in flight.
// Tail windows re-stage the last real K-tile into dead buffers (branch-free);
// post-loop vmcnt(0)+barrier drains all LDS-DMA before any wave retires.
// ============================================================================

#define STAGE_A(b, h, k0)                                                      \
  do {                                                                         \
    async16(gA + (h) * (128L * K_DIM) + (k0),                                  \
            &lds[(b) * 32768 + (h) * 16384 + wave * 1024]);                    \
    async16(gA + (h) * (128L * K_DIM) + 64L * K_DIM + (k0),                    \
            &lds[(b) * 32768 + (h) * 16384 + 8192 + wave * 1024]);             \
  } while (0)

#define STAGE_B(b, h, k0)                                                      \
  do {                                                                         \
    async16(gB + (h) * (128L * K_DIM) + (k0),                                  \
            &lds[65536 + (b) * 32768 + (h) * 16384 + wave * 1024]);            \
    async16(gB + (h) * (128L * K_DIM) + 64L * K_DIM + (k0),                    \
            &lds[65536 + (b) * 32768 + (h) * 16384 + 8192 + wave * 1024]);     \
  } while (0)

#define PHASE(BUF, Q, STAGE_STMT, TAIL_STMT)                                   \
  {                                                                            \
    int32x4 af[2][2];                                                          \
    _Pragma("unroll") for (int kk = 0; kk < 2; ++kk)                           \
    _Pragma("unroll") for (int i2 = 0; i2 < 2; ++i2)                           \
      af[i2][kk] = *(const int32x4*)&lds[(BUF) * 32768 + aoff[kk] +            \
                                         (2 * (Q) + i2) * 2048];               \
    STAGE_STMT;                                                                \
    __builtin_amdgcn_s_barrier();                                              \
    __builtin_amdgcn_s_setprio(1);                                             \
    _Pragma("unroll") for (int kk = 0; kk < 2; ++kk)                           \
    _Pragma("unroll") for (int i2 = 0; i2 < 2; ++i2)                           \
    _Pragma("unroll") for (int fj = 0; fj < 4; ++fj)                           \
      acc[2 * (Q) + i2][fj] = __builtin_amdgcn_mfma_i32_16x16x64_i8(           \
          af[i2][kk], bfr[fj][kk], acc[2 * (Q) + i2][fj], 0, 0, 0);            \
    __builtin_amdgcn_s_setprio(0);                                             \
    TAIL_STMT;                                                                 \
    __builtin_amdgcn_s_barrier();                                              \
  }

#define WINDOW(BUF, KA, KB)                                                    \
  {                                                                            \
    int32x4 bfr[4][2];                                                         \
    _Pragma("unroll") for (int kk = 0; kk < 2; ++kk)                           \
    _Pragma("unroll") for (int fj = 0; fj < 4; ++fj)                           \
      bfr[fj][kk] =                                                            \
          *(const int32x4*)&lds[(BUF) * 32768 + boff[kk] + fj * 2048];         \
    PHASE(BUF, 0, STAGE_A(1 - (BUF), 0, KA), (void)0)                          \
    PHASE(BUF, 1, STAGE_A(1 - (BUF), 1, KA), (void)0)                          \
    PHASE(BUF, 2, STAGE_B(BUF, 0, KB), (void)0)                                \
    PHASE(BUF, 3, STAGE_B(BUF, 1, KB),                                         \
          asm volatile("s_waitcnt vmcnt(4)" ::: "memory"))                     \
  }

__global__ __launch_bounds__(512, 2) void gemm_i8_kernel(
    const signed char* __restrict__ A,
    const signed char* __restrict__ B,
    const float* __restrict__ scales,
    const float* __restrict__ bias,
    float* __restrict__ C) {
  __shared__ __align__(16) signed char lds[131072];

  const int tid  = threadIdx.x;
  const int wave = tid >> 6;
  const int lane = tid & 63;
  const int wm = wave >> 2;   // 0..1: M half (128 rows)
  const int wn = wave & 3;    // 0..3: N quarter (64 cols)
  const int qd = lane >> 4, l16 = lane & 15;

  // T1: XCD-aware swizzle (512 wgs, 512%8==0 -> simple form is bijective)
  int wg = blockIdx.x;
  wg = (wg & 7) * (512 / 8) + (wg >> 3);
  const int bx = wg & 15;   // 16 N-tiles
  const int by = wg >> 4;   // 32 M-tiles
  const long m0 = (long)by * 256;
  const long n0 = (long)bx * 256;

  // staging per-thread source: chunk c = i*512 + tid; row r = i*64 + (tid>>3),
  // physical piece s = tid&7 holds logical piece s ^ (r&7) -> source offset:
  const int roff = tid >> 3;
  const int poff = ((tid & 7) ^ ((tid >> 3) & 7)) << 4;
  const signed char* gA = A + (m0 + roff) * K_DIM + poff;
  const signed char* gB = B + (n0 + roff) * K_DIM + poff;

  // fragment read offsets: row = (wm*128|wn*64) + frag*16 + l16,
  // logical piece kk*4+qd at physical (kk*4+qd) ^ (l16&7)  [row&7 == l16&7]
  const int swz = l16 & 7;
  int aoff[2], boff[2];
#pragma unroll
  for (int kk = 0; kk < 2; ++kk) {
    const int pp = ((kk * 4 + qd) ^ swz) << 4;
    aoff[kk] = (wm * 128 + l16) * 128 + pp;
    boff[kk] = 65536 + (wn * 64 + l16) * 128 + pp;
  }

  int32x4 acc[8][4];
#pragma unroll
  for (int i = 0; i < 8; ++i)
#pragma unroll
    for (int j = 0; j < 4; ++j)
      acc[i][j] = (int32x4){0, 0, 0, 0};

  // prologue: tile0 (A+B) + tile1 B; vmcnt(4) -> tile0 landed, B(1) in flight
  STAGE_A(0, 0, 0);
  STAGE_A(0, 1, 0);
  STAGE_B(0, 0, 0);
  STAGE_B(0, 1, 0);
  STAGE_B(1, 0, 128);
  STAGE_B(1, 1, 128);
  asm volatile("s_waitcnt vmcnt(4)" ::: "memory");
  __builtin_amdgcn_s_barrier();

#pragma unroll 1
  for (int W = 0; W < NT; W += 2) {
    const long kA0 = (long)((W + 1 < NT) ? (W + 1) : (NT - 1)) * 128;
    const long kB0 = (long)((W + 2 < NT) ? (W + 2) : (NT - 1)) * 128;
    WINDOW(0, kA0, kB0)
    const long kA1 = (long)((W + 2 < NT) ? (W + 2) : (NT - 1)) * 128;
    const long kB1 = (long)((W + 3 < NT) ? (W + 3) : (NT - 1)) * 128;
    WINDOW(1, kA1, kB1)
  }

  // drain ALL in-flight LDS-DMA before any wave can retire (an in-flight
  // global_load_lds at s_endpgm writes into deallocated LDS).
  asm volatile("s_waitcnt vmcnt(0)" ::: "memory");
  __builtin_amdgcn_s_barrier();

  // epilogue: C/D layout col=lane&15, row=(lane>>4)*4+reg
  const long row0 = m0 + wm * 128 + qd * 4;
  const long col0 = n0 + wn * 64 + l16;
#pragma unroll
  for (int fj = 0; fj < 4; ++fj) {
    const float bv = bias[col0 + fj * 16];
#pragma unroll
    for (int fi = 0; fi < 8; ++fi) {
      const long r = row0 + fi * 16;
      float4 sv = *(const float4*)&scales[r];
      const float* s = &sv.x;
#pragma unroll
      for (int i = 0; i < 4; ++i) {
        C[(r + i) * N_DIM + col0 + fj * 16] = (float)acc[fi][fj][i] * s[i] + bv;
      }
    }
  }
}

extern "C" void kernel_launch(void* const* d_in, const int* in_sizes, int n_in,
                              void* d_out, int out_size, void* d_ws, size_t ws_size,
                              hipStream_t stream) {
  const float* x    = (const float*)d_in[0];   // [8192, 4096] fp32
  const float* w    = (const float*)d_in[1];   // [4096, 4096] fp32
  const float* bias = (const float*)d_in[2];   // [4096] fp32
  float* out = (float*)d_out;                  // [8192, 4096] fp32

  // workspace: X i8 (32 MB) | W sign i8 (16 MB) | row scales (32 KB)
  signed char* xq = (signed char*)d_ws;
  signed char* wq = xq + (size_t)M_DIM * K_DIM;
  float* scales   = (float*)(wq + (size_t)N_DIM * K_DIM);

  prep_kernel<<<QUANT_BLOCKS + SIGN_BLOCKS, 256, 0, stream>>>(x, w, xq, wq, scales);

  gemm_i8_kernel<<<dim3((M_DIM / 256) * (N_DIM / 256)), dim3(512), 0, stream>>>(
      xq, wq, scales, bias, out);
}

// Round 4
// 390.935 us; speedup vs baseline: 1.0304x; 1.0011x over previous
//
#include <hip/hip_runtime.h>
#include <stdint.h>

#define M_DIM 8192
#define N_DIM 4096
#define K_DIM 4096
#define NT    (K_DIM / 128)  // 32 K-tiles of 128 bytes

typedef __attribute__((ext_vector_type(4))) int int32x4;

// --- Fused prep kernel (unchanged) ---
#define QUANT_BLOCKS 2048
#define SIGN_BLOCKS  1024
#define SIGN_THREADS (SIGN_BLOCKS * 256)

__global__ __launch_bounds__(256) void prep_kernel(const float* __restrict__ x,
                                                   const float* __restrict__ w,
                                                   signed char* __restrict__ xq,
                                                   signed char* __restrict__ wq,
                                                   float* __restrict__ scales) {
  const int bid = blockIdx.x;
  const int t = threadIdx.x;
  if (bid < QUANT_BLOCKS) {
    const int wave = t >> 6, lane = t & 63;
    const int row = bid * 4 + wave;
    const float4* xr = (const float4*)(x + (size_t)row * K_DIM);
    float4 v[16];
    float amax = 0.f;
#pragma unroll
    for (int j = 0; j < 16; j++) {
      v[j] = xr[lane + 64 * j];
      amax = fmaxf(amax, fmaxf(fmaxf(fabsf(v[j].x), fabsf(v[j].y)),
                               fmaxf(fabsf(v[j].z), fabsf(v[j].w))));
    }
#pragma unroll
    for (int off = 32; off > 0; off >>= 1)
      amax = fmaxf(amax, __shfl_xor(amax, off, 64));
    amax = fmaxf(amax, 1e-30f);
    const float rsc = 127.0f / amax;
    if (lane == 0) scales[row] = amax / 127.0f;
    int* qr = (int*)(xq + (size_t)row * K_DIM);
#pragma unroll
    for (int j = 0; j < 16; j++) {
      int q0 = __float2int_rn(v[j].x * rsc);
      int q1 = __float2int_rn(v[j].y * rsc);
      int q2 = __float2int_rn(v[j].z * rsc);
      int q3 = __float2int_rn(v[j].w * rsc);
      qr[lane + 64 * j] = (q0 & 255) | ((q1 & 255) << 8) | ((q2 & 255) << 16) | (q3 << 24);
    }
  } else {
    const int idx0 = (bid - QUANT_BLOCKS) * 256 + t;
    const float4* wf = (const float4*)w;
    int4* o = (int4*)wq;
#pragma unroll
    for (int k = 0; k < 4; k++) {
      const int idx = idx0 + k * SIGN_THREADS;
      int4 pk;
      int* pi = (int*)&pk;
#pragma unroll
      for (int j = 0; j < 4; j++) {
        float4 a = wf[(size_t)idx * 4 + j];
        unsigned b0 = a.x >= 0.f ? 0x01u : 0xFFu;
        unsigned b1 = a.y >= 0.f ? 0x01u : 0xFFu;
        unsigned b2 = a.z >= 0.f ? 0x01u : 0xFFu;
        unsigned b3 = a.w >= 0.f ? 0x01u : 0xFFu;
        pi[j] = (int)(b0 | (b1 << 8) | (b2 << 16) | (b3 << 24));
      }
      o[idx] = pk;
    }
  }
}

// Async global->LDS, 16 B/lane. LDS dest = wave-uniform base + lane*16 (linear);
// the GLOBAL source is per-lane, which is how the XOR swizzle is applied
// (pre-swizzled source, linear dest, swizzled ds_read — both-sides-or-neither).
__device__ __forceinline__ void async16(const signed char* g, signed char* l) {
  __builtin_amdgcn_global_load_lds((const __attribute__((address_space(1))) void*)g,
                                   (__attribute__((address_space(3))) void*)l, 16, 0, 0);
}

// ============================================================================
// 256x256-tile, 8-wave, 4-phase-per-K-tile i8 GEMM.
//
// Round-4 change: REMOVED the mid-phase barrier (between {reads,stage} and
// the MFMA cluster). 4 barriers/K-tile instead of 8. Diagnosis: round-3 phase
// time 1322 cyc vs the proven bf16 template's 745-824 with an identical phase
// skeleton -> ~500 cyc/phase of sync overhead; barriers are the bulk of it.
// Race audit for single-end-barrier phases:
//  * all intra-window LDS wave accesses are READS of buf[cur];
//  * STAGE_A(1-cur) (DMA write) targets a region whose last reads completed
//    before the PREVIOUS window's phase-3 end barrier;
//  * STAGE_B(cur) at phases 2-3 targets the B region whose 8 fragment reads
//    are forced complete (MFMA operand lgkm waits) before every wave's
//    phase-0 END barrier - two end barriers before any stage issue;
//  * vmcnt(4) tail still precedes the phase-3 end barrier, so A(W+1)/B(W+1)
//    visibility at window entry is unchanged.
// Deadlock-impossible: uniform barrier count for all waves. The compiler now
// interleaves each phase's ds_reads under its MFMAs with counted lgkm waits
// (m97 pattern), preserving the fine interleave m196 showed is essential.
//
// LDS map (128 KiB):  A: buf b at b*32768, [256 rows][128 B]
//                     B: buf b at 65536 + b*32768
// Swizzle: row r, logical 16B piece p stored at physical piece p ^ (r&7).
//
// Window W (4 phases) computes tile W from buf[W&1]:
//   phase 0: ds_read 8 B-frags + A-quadrant0 | stage A0(W+1)
//   phase 1: A-quadrant1                     | stage A1(W+1)
//   phase 2: A-quadrant2                     | stage B0(W+2)
//   phase 3: A-quadrant3                     | stage B1(W+2), vmcnt(4)
// Each phase: reads+stage | setprio(1) 16x MFMA setprio(0) | [tail] | barrier.
// Tail windows re-stage the last real K-tile into dead buffers (branch-free);
// post-loop vmcnt(0)+barrier drains all LDS-DMA before any wave retires.
// ============================================================================

#define STAGE_A(b, h, k0)                                                      \
  do {                                                                         \
    async16(gA + (h) * (128L * K_DIM) + (k0),                                  \
            &lds[(b) * 32768 + (h) * 16384 + wave * 1024]);                    \
    async16(gA + (h) * (128L * K_DIM) + 64L * K_DIM + (k0),                    \
            &lds[(b) * 32768 + (h) * 16384 + 8192 + wave * 1024]);             \
  } while (0)

#define STAGE_B(b, h, k0)                                                      \
  do {                                                                         \
    async16(gB + (h) * (128L * K_DIM) + (k0),                                  \
            &lds[65536 + (b) * 32768 + (h) * 16384 + wave * 1024]);            \
    async16(gB + (h) * (128L * K_DIM) + 64L * K_DIM + (k0),                    \
            &lds[65536 + (b) * 32768 + (h) * 16384 + 8192 + wave * 1024]);     \
  } while (0)

#define PHASE(BUF, Q, STAGE_STMT, TAIL_STMT)                                   \
  {                                                                            \
    int32x4 af[2][2];                                                          \
    _Pragma("unroll") for (int kk = 0; kk < 2; ++kk)                           \
    _Pragma("unroll") for (int i2 = 0; i2 < 2; ++i2)                           \
      af[i2][kk] = *(const int32x4*)&lds[(BUF) * 32768 + aoff[kk] +            \
                                         (2 * (Q) + i2) * 2048];               \
    STAGE_STMT;                                                                \
    __builtin_amdgcn_s_setprio(1);                                             \
    _Pragma("unroll") for (int kk = 0; kk < 2; ++kk)                           \
    _Pragma("unroll") for (int i2 = 0; i2 < 2; ++i2)                           \
    _Pragma("unroll") for (int fj = 0; fj < 4; ++fj)                           \
      acc[2 * (Q) + i2][fj] = __builtin_amdgcn_mfma_i32_16x16x64_i8(           \
          af[i2][kk], bfr[fj][kk], acc[2 * (Q) + i2][fj], 0, 0, 0);            \
    __builtin_amdgcn_s_setprio(0);                                             \
    TAIL_STMT;                                                                 \
    __builtin_amdgcn_s_barrier();                                              \
  }

#define WINDOW(BUF, KA, KB)                                                    \
  {                                                                            \
    int32x4 bfr[4][2];                                                         \
    _Pragma("unroll") for (int kk = 0; kk < 2; ++kk)                           \
    _Pragma("unroll") for (int fj = 0; fj < 4; ++fj)                           \
      bfr[fj][kk] =                                                            \
          *(const int32x4*)&lds[(BUF) * 32768 + boff[kk] + fj * 2048];         \
    PHASE(BUF, 0, STAGE_A(1 - (BUF), 0, KA), (void)0)                          \
    PHASE(BUF, 1, STAGE_A(1 - (BUF), 1, KA), (void)0)                          \
    PHASE(BUF, 2, STAGE_B(BUF, 0, KB), (void)0)                                \
    PHASE(BUF, 3, STAGE_B(BUF, 1, KB),                                         \
          asm volatile("s_waitcnt vmcnt(4)" ::: "memory"))                     \
  }

__global__ __launch_bounds__(512, 2) void gemm_i8_kernel(
    const signed char* __restrict__ A,
    const signed char* __restrict__ B,
    const float* __restrict__ scales,
    const float* __restrict__ bias,
    float* __restrict__ C) {
  __shared__ __align__(16) signed char lds[131072];

  const int tid  = threadIdx.x;
  const int wave = tid >> 6;
  const int lane = tid & 63;
  const int wm = wave >> 2;   // 0..1: M half (128 rows)
  const int wn = wave & 3;    // 0..3: N quarter (64 cols)
  const int qd = lane >> 4, l16 = lane & 15;

  // T1: XCD-aware swizzle (512 wgs, 512%8==0 -> simple form is bijective)
  int wg = blockIdx.x;
  wg = (wg & 7) * (512 / 8) + (wg >> 3);
  const int bx = wg & 15;   // 16 N-tiles
  const int by = wg >> 4;   // 32 M-tiles
  const long m0 = (long)by * 256;
  const long n0 = (long)bx * 256;

  // staging per-thread source: chunk c = i*512 + tid; row r = i*64 + (tid>>3),
  // physical piece s = tid&7 holds logical piece s ^ (r&7) -> source offset:
  const int roff = tid >> 3;
  const int poff = ((tid & 7) ^ ((tid >> 3) & 7)) << 4;
  const signed char* gA = A + (m0 + roff) * K_DIM + poff;
  const signed char* gB = B + (n0 + roff) * K_DIM + poff;

  // fragment read offsets: row = (wm*128|wn*64) + frag*16 + l16,
  // logical piece kk*4+qd at physical (kk*4+qd) ^ (l16&7)  [row&7 == l16&7]
  const int swz = l16 & 7;
  int aoff[2], boff[2];
#pragma unroll
  for (int kk = 0; kk < 2; ++kk) {
    const int pp = ((kk * 4 + qd) ^ swz) << 4;
    aoff[kk] = (wm * 128 + l16) * 128 + pp;
    boff[kk] = 65536 + (wn * 64 + l16) * 128 + pp;
  }

  int32x4 acc[8][4];
#pragma unroll
  for (int i = 0; i < 8; ++i)
#pragma unroll
    for (int j = 0; j < 4; ++j)
      acc[i][j] = (int32x4){0, 0, 0, 0};

  // prologue: tile0 (A+B) + tile1 B; vmcnt(4) -> tile0 landed, B(1) in flight
  STAGE_A(0, 0, 0);
  STAGE_A(0, 1, 0);
  STAGE_B(0, 0, 0);
  STAGE_B(0, 1, 0);
  STAGE_B(1, 0, 128);
  STAGE_B(1, 1, 128);
  asm volatile("s_waitcnt vmcnt(4)" ::: "memory");
  __builtin_amdgcn_s_barrier();

#pragma unroll 1
  for (int W = 0; W < NT; W += 2) {
    const long kA0 = (long)((W + 1 < NT) ? (W + 1) : (NT - 1)) * 128;
    const long kB0 = (long)((W + 2 < NT) ? (W + 2) : (NT - 1)) * 128;
    WINDOW(0, kA0, kB0)
    const long kA1 = (long)((W + 2 < NT) ? (W + 2) : (NT - 1)) * 128;
    const long kB1 = (long)((W + 3 < NT) ? (W + 3) : (NT - 1)) * 128;
    WINDOW(1, kA1, kB1)
  }

  // drain ALL in-flight LDS-DMA before any wave can retire (an in-flight
  // global_load_lds at s_endpgm writes into deallocated LDS).
  asm volatile("s_waitcnt vmcnt(0)" ::: "memory");
  __builtin_amdgcn_s_barrier();

  // epilogue: C/D layout col=lane&15, row=(lane>>4)*4+reg
  const long row0 = m0 + wm * 128 + qd * 4;
  const long col0 = n0 + wn * 64 + l16;
#pragma unroll
  for (int fj = 0; fj < 4; ++fj) {
    const float bv = bias[col0 + fj * 16];
#pragma unroll
    for (int fi = 0; fi < 8; ++fi) {
      const long r = row0 + fi * 16;
      float4 sv = *(const float4*)&scales[r];
      const float* s = &sv.x;
#pragma unroll
      for (int i = 0; i < 4; ++i) {
        C[(r + i) * N_DIM + col0 + fj * 16] = (float)acc[fi][fj][i] * s[i] + bv;
      }
    }
  }
}

extern "C" void kernel_launch(void* const* d_in, const int* in_sizes, int n_in,
                              void* d_out, int out_size, void* d_ws, size_t ws_size,
                              hipStream_t stream) {
  const float* x    = (const float*)d_in[0];   // [8192, 4096] fp32
  const float* w    = (const float*)d_in[1];   // [4096, 4096] fp32
  const float* bias = (const float*)d_in[2];   // [4096] fp32
  float* out = (float*)d_out;                  // [8192, 4096] fp32

  // workspace: X i8 (32 MB) | W sign i8 (16 MB) | row scales (32 KB)
  signed char* xq = (signed char*)d_ws;
  signed char* wq = xq + (size_t)M_DIM * K_DIM;
  float* scales   = (float*)(wq + (size_t)N_DIM * K_DIM);

  prep_kernel<<<QUANT_BLOCKS + SIGN_BLOCKS, 256, 0, stream>>>(x, w, xq, wq, scales);

  gemm_i8_kernel<<<dim3((M_DIM / 256) * (N_DIM / 256)), dim3(512), 0, stream>>>(
      xq, wq, scales, bias, out);
}